// Round 16
// baseline (870.544 us; speedup 1.0000x reference)
//
#include <hip/hip_runtime.h>
#include <cfloat>
#include <math.h>

#define D_DIM 1024
#define B_DIM 4
#define NQ    1024
#define NC    16384
#define TOPN  5
#define TOPA  5               // stage-A candidates per context split
#define CSPLIT 8              // context splits per batch
#define CAND  (TOPA*CSPLIT)   // 40 candidates per query
#define QT    64              // queries per block (dist kernel)
#define CTILE 512             // contexts per tile iteration (128 per wave x 4 waves)
#define BK    64              // K per LDS stage (bf16 elements)

// proj (fp64 MFMA) tiling
#define PBM 128
#define PBN 64
#define PBK 32
#define PROJ_BLKS ((D_DIM/PBN) * ((B_DIM*NQ)/PBM))   // 512

typedef __bf16 bf16x8 __attribute__((ext_vector_type(8)));
typedef float  f32x4  __attribute__((ext_vector_type(4)));
typedef double f64x4  __attribute__((ext_vector_type(4)));

__device__ __forceinline__ unsigned short f2bf(float f) {
    unsigned u = __builtin_bit_cast(unsigned, f);
    unsigned r = (u + 0x7fffu + ((u >> 16) & 1u)) >> 16;
    return (unsigned short)r;
}

// async global->LDS, 16B per lane; LDS dest = wave-uniform base + lane*16
__device__ __forceinline__ void gload16(const void* g, void* l) {
    __builtin_amdgcn_global_load_lds(
        (const __attribute__((address_space(1))) unsigned*)g,
        (__attribute__((address_space(3))) unsigned*)l, 16, 0, 0);
}

// ---- lexicographic (value, index) top-N insert (used by fp64 refine) ----
template<int N, typename T>
__device__ __forceinline__ void topk_insert(T (&bv)[N], int (&bi)[N], T v, int ci) {
    if (v < bv[N-1] || (v == bv[N-1] && ci < bi[N-1])) {
        bv[N-1] = v; bi[N-1] = ci;
        #pragma unroll
        for (int s = N-1; s > 0; --s) {
            bool sw = (bv[s] < bv[s-1]) || (bv[s] == bv[s-1] && bi[s] < bi[s-1]);
            if (sw) {
                T tv = bv[s-1]; bv[s-1] = bv[s]; bv[s] = tv;
                int ti = bi[s-1]; bi[s-1] = bi[s]; bi[s] = ti;
            }
        }
    }
}

// ---- value-only top-N insert (merge phases; ties resolved by fp64 refine) ----
template<int N>
__device__ __forceinline__ void insN(float (&bv)[N], int (&bi)[N], float v, int ci) {
    if (v < bv[N-1]) {
        bv[N-1] = v; bi[N-1] = ci;
        #pragma unroll
        for (int s = N-1; s > 0; --s) {
            if (bv[s] < bv[s-1]) {
                float tv = bv[s-1]; bv[s-1] = bv[s]; bv[s] = tv;
                int   ti = bi[s-1]; bi[s-1] = bi[s]; bi[s] = ti;
            }
        }
    }
}

// ---- branchless sorted (value,index) top-5 insert for the hot acc drain ----
__device__ __forceinline__ void ins5b(float (&bv)[TOPA], int (&bi)[TOPA], float v, int ci) {
    #pragma unroll
    for (int s = 0; s < TOPA; ++s) {
        const bool  c    = v < bv[s];
        const float vmin = c ? v : bv[s];
        const float vmax = c ? bv[s] : v;
        const int   imin = c ? ci : bi[s];
        const int   imax = c ? bi[s] : ci;
        bv[s] = vmin; bi[s] = imin;
        v = vmax; ci = imax;
    }
}

// ---- Kernel 1 (fat): blocks [0,512) = fp64-MFMA projection (+ fused pack_q
// epilogue); rest = pack C.  Pbf/qsq/pi are PHYSICAL-row ordered; refine reads
// via invperm -- correct for ANY within-16 row perm of the f64 MFMA.
// R16: global_load_lds double-buffer staging for proj (T3-minimum structure).
// R15's reg-staged T14 regressed (VGPR 84->104 cut waves/SIMD 6->4); gload_lds
// costs ZERO VGPRs. proj's compute phase (64 f64 MFMA ~= 1024 cy at 16 cy/MFMA)
// >> load latency, so issue-before-compute fully hides it (unlike dist's R4
// where the 16-MFMA phase was too short). LDS tiles unpadded [row][32] with
// source-side XOR swizzle (rule #21: linear dest + inv-swz source + swz read):
// element (row,kc) at row*32 + ((kc>>2)^(row&7))*4 + (kc&3); fragment reads
// (kc = ks*4+l4, ks uniform, row&7 = l15&7) hit 32 banks 2-way = free.
__global__ __launch_bounds__(256) void proj_packc_kernel(const float* __restrict__ Q,
                                                         const float* __restrict__ W,
                                                         const float* __restrict__ bias,
                                                         const float* __restrict__ C,
                                                         double* __restrict__ P64,
                                                         unsigned short* __restrict__ Pbf,
                                                         float* __restrict__ qsq,
                                                         unsigned short* __restrict__ Cbf,
                                                         float* __restrict__ csq)
{
    const int bid = blockIdx.x;
    if (bid >= PROJ_BLKS) {
        // ---------------- pack_c branch ----------------
        int wave = threadIdx.x >> 6;
        int lane = threadIdx.x & 63;
        int row  = (bid - PROJ_BLKS) * 4 + wave;
        const float* x = C + (size_t)row * D_DIM;
        float s = 0.f;
        #pragma unroll
        for (int i = 0; i < 4; ++i) {
            float4 v = *(const float4*)&x[lane * 4 + i * 256];
            s += v.x * v.x + v.y * v.y + v.z * v.z + v.w * v.w;
            ushort4 h;
            h.x = f2bf(v.x); h.y = f2bf(v.y); h.z = f2bf(v.z); h.w = f2bf(v.w);
            *(ushort4*)&Cbf[(size_t)row * D_DIM + lane * 4 + i * 256] = h;
        }
        #pragma unroll
        for (int off = 32; off; off >>= 1) s += __shfl_down(s, off, 64);
        if (lane == 0) csq[row] = s;
        return;
    }
    // ---------------- proj branch ----------------
    __shared__ __align__(16) float QsL[2][PBM * PBK];   // 2 x 16 KB
    __shared__ __align__(16) float WsL[2][PBN * PBK];   // 2 x  8 KB

    const int t    = threadIdx.x;
    const int lane = t & 63;
    const int w    = t >> 6;          // wave 0..3
    const int l15  = lane & 15;
    const int l4   = lane >> 4;       // 0..3
    const int r8   = lane >> 3;       // staging sub-row 0..7
    const int sc   = lane & 7;        // staging store-chunk 0..7 (16 B each)
    const int m0   = (bid >> 4) * PBM;
    const int n0   = (bid & 15) * PBN;
    const int wm   = (w >> 1) * 64;   // wave row offset in tile
    const int wn   = (w & 1) * 32;    // wave col offset in tile

    f64x4 acc[4][2];
    #pragma unroll
    for (int fm = 0; fm < 4; ++fm)
        #pragma unroll
        for (int fn = 0; fn < 2; ++fn) acc[fm][fn] = (f64x4)0.0;

    // wave w stages Q rows w*32..+31 (4 gloads) and W rows w*16..+15 (2 gloads)
    // source chunk = sc ^ r8 (row&7); LDS dest linear -> LDS[row][chunk sc]
    // holds global chunk sc^(row&7).
    auto stage = [&](int k0, int b) {
        #pragma unroll
        for (int j = 0; j < 4; ++j)
            gload16(&Q[(size_t)(m0 + w * 32 + j * 8 + r8) * D_DIM + k0 + (sc ^ r8) * 4],
                    &QsL[b][(w * 32 + j * 8) * PBK]);
        #pragma unroll
        for (int j = 0; j < 2; ++j)
            gload16(&W[(size_t)(n0 + w * 16 + j * 8 + r8) * D_DIM + k0 + (sc ^ r8) * 4],
                    &WsL[b][(w * 16 + j * 8) * PBK]);
    };

    stage(0, 0);
    __syncthreads();   // prologue tile resident
    int cur = 0;

    for (int k0 = 0; k0 < D_DIM; k0 += PBK) {
        if (k0 + PBK < D_DIM) stage(k0 + PBK, cur ^ 1);   // ~1024 cy of MFMA below hides latency

        #pragma unroll
        for (int ks = 0; ks < PBK / 4; ++ks) {
            const int sw = ((ks ^ (l15 & 7)) << 2) + l4;   // swizzled in-row offset for kc=ks*4+l4
            double a[4], b[2];
            #pragma unroll
            for (int fm = 0; fm < 4; ++fm)
                a[fm] = (double)QsL[cur][(wm + fm * 16 + l15) * PBK + sw];
            #pragma unroll
            for (int fn = 0; fn < 2; ++fn)
                b[fn] = (double)WsL[cur][(wn + fn * 16 + l15) * PBK + sw];
            #pragma unroll
            for (int fm = 0; fm < 4; ++fm)
                #pragma unroll
                for (int fn = 0; fn < 2; ++fn)
                    acc[fm][fn] = __builtin_amdgcn_mfma_f64_16x16x4f64(a[fm], b[fn], acc[fm][fn], 0, 0, 0);
        }

        __syncthreads();   // next tile's loads drained (cheap: issued ~1024 cy ago);
        cur ^= 1;          // all reads of cur done before it is overwritten next iter
    }

    // fused epilogue: P64 + bf16 Pbf + fp32 qsq (16-lane reduce + atomicAdd)
    #pragma unroll
    for (int fm = 0; fm < 4; ++fm) {
        #pragma unroll
        for (int j = 0; j < 4; ++j) {
            const int row = m0 + wm + fm * 16 + j * 4 + l4;   // physical row
            float part = 0.f;
            #pragma unroll
            for (int fn = 0; fn < 2; ++fn) {
                const int col = n0 + wn + fn * 16 + l15;
                double d = acc[fm][fn][j] + (double)bias[col];
                P64[(size_t)row * D_DIM + col] = d;
                float a = (float)d;
                part += a * a;
                Pbf[(size_t)row * D_DIM + col] = f2bf(a);
            }
            #pragma unroll
            for (int m = 1; m < 16; m <<= 1) part += __shfl_xor(part, m, 64);
            if (l15 == 0) atomicAdd(&qsq[row], part);
        }
    }
}

// ---- Kernel 1b: measure the actual within-16 row permutation of P64 ----
__global__ __launch_bounds__(256) void perm_detect_kernel(const float* __restrict__ Q,
                                                          const float* __restrict__ W,
                                                          const float* __restrict__ bias,
                                                          const double* __restrict__ P64,
                                                          int* __restrict__ invperm)
{
    __shared__ double tv[16];
    const int t = threadIdx.x;      // 256 threads
    const int g = t >> 4;           // true row 0..15
    const int s = t & 15;           // k-slice
    if (t < 16) invperm[t] = t;     // identity default (overwritten below)

    double acc = 0.0;
    const int kb = s * 64;
    for (int k = 0; k < 64; ++k)
        acc = fma((double)Q[(size_t)g * D_DIM + kb + k], (double)W[kb + k], acc);
    #pragma unroll
    for (int off = 8; off; off >>= 1) acc += __shfl_down(acc, off, 16);
    if (s == 0) tv[g] = acc + (double)bias[0];
    __syncthreads();

    if (t < 16) {
        double p = P64[(size_t)t * D_DIM];   // physical row t, col 0
        int best = 0; double bd = fabs(p - tv[0]);
        #pragma unroll
        for (int i = 1; i < 16; ++i) {
            double d = fabs(p - tv[i]);
            if (d < bd) { bd = d; best = i; }
        }
        invperm[best] = t;   // physical row t holds true row `best`
    }
}

// ---- Kernel 4: bf16-MFMA screening GEMM + per-lane register top-5 ----
// R14/R11 configuration (measured 231-233us, best of 7 structural variants).
__global__ __launch_bounds__(256, 2) void dist_mfma_kernel(const unsigned short* __restrict__ Pbf,
                                                           const unsigned short* __restrict__ Cbf,
                                                           const float* __restrict__ qsq,
                                                           const float* __restrict__ csq,
                                                           int* __restrict__ pi)
{
    __shared__ __align__(16) short CsS[CTILE * 64];  // 64 KB
    __shared__ __align__(16) short QsS[QT * 64];     //  8 KB
    float* MV = (float*)CsS;                         // merge alias: [64][4][TOPA]
    int*   MI = (int*)(CsS + 4096);                  // 8 KB offset

    const int t    = threadIdx.x;
    const int lane = t & 63;
    const int w    = t >> 6;       // wave 0..3 -> 128-context strip
    const int l15  = lane & 15;
    const int l4   = lane >> 4;    // 0..3
    const int r8   = lane >> 3;    // 0..7 (staging sub-row)
    const int sc   = lane & 7;     // staging store-chunk
    const int csplit = blockIdx.x;
    const int by = blockIdx.y;
    const int bz = blockIdx.z;
    const int qg0 = bz * NQ + by * QT;

    // loop-invariant lane-relative staging offsets (elements)
    unsigned cOff[16], qOff[2];
    #pragma unroll
    for (int j = 0; j < 16; ++j)
        cOff[j] = (unsigned)((w * 128 + j * 8 + r8) * D_DIM + (sc ^ r8) * 8);
    #pragma unroll
    for (int j = 0; j < 2; ++j)
        qOff[j] = (unsigned)((w * 16 + j * 8 + r8) * D_DIM + (sc ^ r8) * 8);

    float qsv[4];
    #pragma unroll
    for (int s = 0; s < 4; ++s) qsv[s] = qsq[qg0 + s * 16 + l15];

    float bv[4][TOPA]; int bi[4][TOPA];
    #pragma unroll
    for (int s = 0; s < 4; ++s)
        #pragma unroll
        for (int j = 0; j < TOPA; ++j) { bv[s][j] = FLT_MAX; bi[s][j] = 0x7fffffff; }

    const int cpb = NC / CSPLIT;   // 2048
    for (int it = 0; it < cpb / CTILE; ++it) {       // 4 iterations
        const int cg0 = csplit * cpb + it * CTILE;
        const size_t crow0 = (size_t)bz * NC + cg0;

        f32x4 acc[8][4];
        #pragma unroll
        for (int u = 0; u < 8; ++u)
            #pragma unroll
            for (int s = 0; s < 4; ++s) acc[u][s] = (f32x4)0.0f;

        for (int k0 = 0; k0 < D_DIM; k0 += BK) {
            const unsigned short* cB = Cbf + crow0 * D_DIM + k0;
            const unsigned short* qB = Pbf + (size_t)qg0 * D_DIM + k0;
            __syncthreads();   // all waves done reading previous LDS contents
            #pragma unroll
            for (int j = 0; j < 16; ++j)
                gload16(cB + cOff[j], &CsS[(w * 128 + j * 8) * 64]);
            #pragma unroll
            for (int j = 0; j < 2; ++j)
                gload16(qB + qOff[j], &QsS[(w * 16 + j * 8) * 64]);
            __syncthreads();   // vmcnt drained before barrier -> LDS filled
            #pragma unroll
            for (int ks = 0; ks < 2; ++ks) {
                const int sp = ((ks * 4 + l4) ^ (l15 & 7)) * 8;
                bf16x8 bq[4];
                #pragma unroll
                for (int s = 0; s < 4; ++s)
                    bq[s] = *(const bf16x8*)&QsS[(s * 16 + l15) * 64 + sp];
                #pragma unroll
                for (int u = 0; u < 8; ++u) {
                    bf16x8 ac = *(const bf16x8*)&CsS[(w * 128 + u * 16 + l15) * 64 + sp];
                    #pragma unroll
                    for (int s = 0; s < 4; ++s)
                        acc[u][s] = __builtin_amdgcn_mfma_f32_16x16x32_bf16(ac, bq[s], acc[u][s], 0, 0, 0);
                }
            }
        }

        // d^2 = |q|^2 + |c|^2 - 2 q.c  -> branchless per-lane register top-5
        #pragma unroll
        for (int u = 0; u < 8; ++u) {
            const int crow = w * 128 + u * 16 + l4 * 4;
            float4 cs4 = *(const float4*)&csq[(size_t)bz * NC + cg0 + crow];
            float csa[4] = {cs4.x, cs4.y, cs4.z, cs4.w};
            #pragma unroll
            for (int s = 0; s < 4; ++s) {
                #pragma unroll
                for (int r = 0; r < 4; ++r) {
                    float v = qsv[s] + csa[r] - 2.0f * acc[u][s][r];
                    ins5b(bv[s], bi[s], v, cg0 + crow + r);
                }
            }
        }
    }

    // wave-level merge across l4 groups (same query columns) via shuffles
    #pragma unroll
    for (int mask = 16; mask <= 32; mask <<= 1) {
        #pragma unroll
        for (int s = 0; s < 4; ++s) {
            float ov[TOPA]; int oi[TOPA];
            #pragma unroll
            for (int j = 0; j < TOPA; ++j) {
                ov[j] = __shfl_xor(bv[s][j], mask, 64);
                oi[j] = __shfl_xor(bi[s][j], mask, 64);
            }
            #pragma unroll
            for (int j = 0; j < TOPA; ++j) insN<TOPA>(bv[s], bi[s], ov[j], oi[j]);
        }
    }
    // cross-wave merge via LDS (l4==0 lanes hold wave-merged lists)
    __syncthreads();
    if (l4 == 0) {
        #pragma unroll
        for (int s = 0; s < 4; ++s) {
            int q = s * 16 + l15;
            #pragma unroll
            for (int j = 0; j < TOPA; ++j) {
                MV[(q * 4 + w) * TOPA + j] = bv[s][j];
                MI[(q * 4 + w) * TOPA + j] = bi[s][j];
            }
        }
    }
    __syncthreads();
    if (t < QT) {
        float mv[TOPA]; int mi[TOPA];
        #pragma unroll
        for (int j = 0; j < TOPA; ++j) { mv[j] = FLT_MAX; mi[j] = 0x7fffffff; }
        for (int l = 0; l < 4; ++l)
            #pragma unroll
            for (int j = 0; j < TOPA; ++j)
                insN<TOPA>(mv, mi, MV[(t * 4 + l) * TOPA + j], MI[(t * 4 + l) * TOPA + j]);
        size_t base = (((size_t)qg0 + t) * CSPLIT + csplit) * TOPA;
        #pragma unroll
        for (int j = 0; j < TOPA; ++j) pi[base + j] = mi[j];
    }
}

// ---- Kernel 5: fp64 exact refine of 40 candidates per query -> top-5, sqrt, outputs ----
__global__ __launch_bounds__(256) void refine_kernel(const double* __restrict__ P64,
                                                     const int* __restrict__ invperm,
                                                     const float* __restrict__ C,
                                                     const int*   __restrict__ pi,
                                                     float* __restrict__ out)
{
    __shared__ double pS[D_DIM];   // 8 KB staged P-row
    __shared__ double dvs[CAND];
    __shared__ int    dis[CAND];
    const int q    = blockIdx.x;                      // true row
    const int pq   = (q & ~15) | invperm[q & 15];     // physical row (P64, Pbf, pi)
    const int bz   = q >> 10;
    const int t    = threadIdx.x;
    const int wave = t >> 6;
    const int lane = t & 63;
    const double* p = P64 + (size_t)pq * D_DIM;

    #pragma unroll
    for (int j = 0; j < D_DIM / 256; ++j) pS[t + j * 256] = p[t + j * 256];
    __syncthreads();

    for (int k = wave; k < CAND; k += 4) {
        int ci = pi[(size_t)pq * CAND + k];
        const float* c = C + ((size_t)bz * NC + ci) * D_DIM;
        double s = 0.0;
        #pragma unroll
        for (int j = 0; j < 16; ++j) {
            int d = lane + 64 * j;
            double diff = pS[d] - (double)c[d];
            s = fma(diff, diff, s);
        }
        #pragma unroll
        for (int off = 32; off; off >>= 1) s += __shfl_down(s, off, 64);
        if (lane == 0) { dvs[k] = s; dis[k] = ci; }
    }
    __syncthreads();
    if (t == 0) {
        double bv[TOPN]; int bi[TOPN];
        #pragma unroll
        for (int j = 0; j < TOPN; ++j) { bv[j] = DBL_MAX; bi[j] = 0x7fffffff; }
        for (int k = 0; k < CAND; ++k)
            topk_insert<TOPN,double>(bv, bi, dvs[k], dis[k]);
        #pragma unroll
        for (int j = 0; j < TOPN; ++j) {
            out[(size_t)q * TOPN + j] = (float)sqrt(bv[j]);
            out[(size_t)B_DIM * NQ * TOPN + (size_t)q * TOPN + j] = (float)bi[j];
        }
    }
}

extern "C" void kernel_launch(void* const* d_in, const int* in_sizes, int n_in,
                              void* d_out, int out_size, void* d_ws, size_t ws_size,
                              hipStream_t stream) {
    const float* Q    = (const float*)d_in[0];
    const float* C    = (const float*)d_in[1];
    const float* W    = (const float*)d_in[2];
    const float* bias = (const float*)d_in[3];
    float* out = (float*)d_out;

    char* ws = (char*)d_ws;
    double*         P64 = (double*)ws;                                       // 32 MB
    unsigned short* Pbf = (unsigned short*)(ws + (size_t)32 * 1024 * 1024);  //  8 MB
    unsigned short* Cbf = (unsigned short*)(ws + (size_t)40 * 1024 * 1024);  // 128 MB
    float*          qsq = (float*)(ws + (size_t)168 * 1024 * 1024);          // 16 KB
    float*          csq = qsq + 4096;                                        // 256 KB
    int*            pi  = (int*)(csq + 65536);                               // 655 KB
    int*            ivp = pi + (size_t)B_DIM * NQ * CAND;                    // 64 B
    // total ~170 MB of workspace

    hipMemsetAsync(qsq, 0, (size_t)B_DIM * NQ * sizeof(float), stream);  // qsq accumulated by atomics
    proj_packc_kernel<<<PROJ_BLKS + (B_DIM * NC) / 4, 256, 0, stream>>>(Q, W, bias, C, P64, Pbf, qsq, Cbf, csq);
    perm_detect_kernel<<<1, 256, 0, stream>>>(Q, W, bias, P64, ivp);
    dist_mfma_kernel<<<dim3(CSPLIT, NQ / QT, B_DIM), 256, 0, stream>>>(Pbf, Cbf, qsq, csq, pi);
    refine_kernel<<<B_DIM * NQ, 256, 0, stream>>>(P64, ivp, C, pi, out);
}

// Round 17
// 837.224 us; speedup vs baseline: 1.0398x; 1.0398x over previous
//
#include <hip/hip_runtime.h>
#include <cfloat>
#include <math.h>

#define D_DIM 1024
#define B_DIM 4
#define NQ    1024
#define NC    16384
#define TOPN  5
#define TOPA  5               // stage-A candidates per context split
#define CSPLIT 8              // context splits per batch
#define CAND  (TOPA*CSPLIT)   // 40 candidates per query
#define QT    64              // queries per block (dist kernel)
#define CTILE 512             // contexts per tile iteration (128 per wave x 4 waves)
#define BK    64              // K per LDS stage (bf16 elements)

// proj (fp64 MFMA) tiling
#define PBM 128
#define PBN 64
#define PBK 32
#define PPAD 4
#define PROJ_BLKS ((D_DIM/PBN) * ((B_DIM*NQ)/PBM))   // 512

typedef __bf16 bf16x8 __attribute__((ext_vector_type(8)));
typedef float  f32x4  __attribute__((ext_vector_type(4)));
typedef double f64x4  __attribute__((ext_vector_type(4)));

__device__ __forceinline__ unsigned short f2bf(float f) {
    unsigned u = __builtin_bit_cast(unsigned, f);
    unsigned r = (u + 0x7fffu + ((u >> 16) & 1u)) >> 16;
    return (unsigned short)r;
}

// async global->LDS, 16B per lane; LDS dest = wave-uniform base + lane*16
__device__ __forceinline__ void gload16(const void* g, void* l) {
    __builtin_amdgcn_global_load_lds(
        (const __attribute__((address_space(1))) unsigned*)g,
        (__attribute__((address_space(3))) unsigned*)l, 16, 0, 0);
}

// ---- lexicographic (value, index) top-N insert (used by fp64 refine) ----
template<int N, typename T>
__device__ __forceinline__ void topk_insert(T (&bv)[N], int (&bi)[N], T v, int ci) {
    if (v < bv[N-1] || (v == bv[N-1] && ci < bi[N-1])) {
        bv[N-1] = v; bi[N-1] = ci;
        #pragma unroll
        for (int s = N-1; s > 0; --s) {
            bool sw = (bv[s] < bv[s-1]) || (bv[s] == bv[s-1] && bi[s] < bi[s-1]);
            if (sw) {
                T tv = bv[s-1]; bv[s-1] = bv[s]; bv[s] = tv;
                int ti = bi[s-1]; bi[s-1] = bi[s]; bi[s] = ti;
            }
        }
    }
}

// ---- value-only top-N insert (merge phases; ties resolved by fp64 refine) ----
template<int N>
__device__ __forceinline__ void insN(float (&bv)[N], int (&bi)[N], float v, int ci) {
    if (v < bv[N-1]) {
        bv[N-1] = v; bi[N-1] = ci;
        #pragma unroll
        for (int s = N-1; s > 0; --s) {
            if (bv[s] < bv[s-1]) {
                float tv = bv[s-1]; bv[s-1] = bv[s]; bv[s] = tv;
                int   ti = bi[s-1]; bi[s-1] = bi[s]; bi[s] = ti;
            }
        }
    }
}

// ---- branchless sorted (value,index) top-5 insert for the hot acc drain ----
__device__ __forceinline__ void ins5b(float (&bv)[TOPA], int (&bi)[TOPA], float v, int ci) {
    #pragma unroll
    for (int s = 0; s < TOPA; ++s) {
        const bool  c    = v < bv[s];
        const float vmin = c ? v : bv[s];
        const float vmax = c ? bv[s] : v;
        const int   imin = c ? ci : bi[s];
        const int   imax = c ? bi[s] : ci;
        bv[s] = vmin; bi[s] = imin;
        v = vmax; ci = imax;
    }
}

// ---- Kernel 1 (fat): blocks [0,512) = fp64-MFMA projection (+ fused pack_q
// epilogue); rest = pack C.  Pbf/qsq/pi are PHYSICAL-row ordered; refine reads
// via invperm -- correct for ANY within-16 row perm of the f64 MFMA.
// R17: byte-exact R14 configuration (measured 838.2/839.6 twice). Both proj
// pipelining attempts regressed by destroying TLP: R15 reg-staged (+20 VGPR,
// waves/SIMD 6->4, 250us), R16 gload_lds dbuf (+21KB LDS, occupancy 31->21%,
// 267us). proj's latency hiding comes from 5-6 co-resident blocks.
__global__ __launch_bounds__(256) void proj_packc_kernel(const float* __restrict__ Q,
                                                         const float* __restrict__ W,
                                                         const float* __restrict__ bias,
                                                         const float* __restrict__ C,
                                                         double* __restrict__ P64,
                                                         unsigned short* __restrict__ Pbf,
                                                         float* __restrict__ qsq,
                                                         unsigned short* __restrict__ Cbf,
                                                         float* __restrict__ csq)
{
    const int bid = blockIdx.x;
    if (bid >= PROJ_BLKS) {
        // ---------------- pack_c branch ----------------
        int wave = threadIdx.x >> 6;
        int lane = threadIdx.x & 63;
        int row  = (bid - PROJ_BLKS) * 4 + wave;
        const float* x = C + (size_t)row * D_DIM;
        float s = 0.f;
        #pragma unroll
        for (int i = 0; i < 4; ++i) {
            float4 v = *(const float4*)&x[lane * 4 + i * 256];
            s += v.x * v.x + v.y * v.y + v.z * v.z + v.w * v.w;
            ushort4 h;
            h.x = f2bf(v.x); h.y = f2bf(v.y); h.z = f2bf(v.z); h.w = f2bf(v.w);
            *(ushort4*)&Cbf[(size_t)row * D_DIM + lane * 4 + i * 256] = h;
        }
        #pragma unroll
        for (int off = 32; off; off >>= 1) s += __shfl_down(s, off, 64);
        if (lane == 0) csq[row] = s;
        return;
    }
    // ---------------- proj branch ----------------
    __shared__ __align__(16) float Qs[PBM][PBK + PPAD];   // 18 KB
    __shared__ __align__(16) float Ws[PBN][PBK + PPAD];   //  9 KB

    const int t    = threadIdx.x;
    const int lane = t & 63;
    const int w    = t >> 6;          // wave 0..3
    const int l15  = lane & 15;
    const int l4   = lane >> 4;       // 0..3
    const int m0   = (bid >> 4) * PBM;
    const int n0   = (bid & 15) * PBN;
    const int wm   = (w >> 1) * 64;   // wave row offset in tile
    const int wn   = (w & 1) * 32;    // wave col offset in tile

    const int srow = t >> 3;          // 0..31 staging row
    const int scol = (t & 7) * 4;     // staging float4 col (0..28)

    f64x4 acc[4][2];
    #pragma unroll
    for (int fm = 0; fm < 4; ++fm)
        #pragma unroll
        for (int fn = 0; fn < 2; ++fn) acc[fm][fn] = (f64x4)0.0;

    for (int k0 = 0; k0 < D_DIM; k0 += PBK) {
        float4 qa0 = *(const float4*)&Q[(size_t)(m0 + srow)      * D_DIM + k0 + scol];
        float4 qa1 = *(const float4*)&Q[(size_t)(m0 + srow + 32) * D_DIM + k0 + scol];
        float4 qa2 = *(const float4*)&Q[(size_t)(m0 + srow + 64) * D_DIM + k0 + scol];
        float4 qa3 = *(const float4*)&Q[(size_t)(m0 + srow + 96) * D_DIM + k0 + scol];
        float4 wa0 = *(const float4*)&W[(size_t)(n0 + srow)      * D_DIM + k0 + scol];
        float4 wa1 = *(const float4*)&W[(size_t)(n0 + srow + 32) * D_DIM + k0 + scol];
        __syncthreads();   // previous-iteration readers done
        *(float4*)&Qs[srow][scol]      = qa0;
        *(float4*)&Qs[srow + 32][scol] = qa1;
        *(float4*)&Qs[srow + 64][scol] = qa2;
        *(float4*)&Qs[srow + 96][scol] = qa3;
        *(float4*)&Ws[srow][scol]      = wa0;
        *(float4*)&Ws[srow + 32][scol] = wa1;
        __syncthreads();   // tile visible to all waves

        #pragma unroll
        for (int ks = 0; ks < PBK / 4; ++ks) {
            const int kc = ks * 4 + l4;
            double a[4], b[2];
            #pragma unroll
            for (int fm = 0; fm < 4; ++fm) a[fm] = (double)Qs[wm + fm * 16 + l15][kc];
            #pragma unroll
            for (int fn = 0; fn < 2; ++fn) b[fn] = (double)Ws[wn + fn * 16 + l15][kc];
            #pragma unroll
            for (int fm = 0; fm < 4; ++fm)
                #pragma unroll
                for (int fn = 0; fn < 2; ++fn)
                    acc[fm][fn] = __builtin_amdgcn_mfma_f64_16x16x4f64(a[fm], b[fn], acc[fm][fn], 0, 0, 0);
        }
    }

    // fused epilogue: P64 + bf16 Pbf + fp32 qsq (16-lane reduce + atomicAdd)
    #pragma unroll
    for (int fm = 0; fm < 4; ++fm) {
        #pragma unroll
        for (int j = 0; j < 4; ++j) {
            const int row = m0 + wm + fm * 16 + j * 4 + l4;   // physical row
            float part = 0.f;
            #pragma unroll
            for (int fn = 0; fn < 2; ++fn) {
                const int col = n0 + wn + fn * 16 + l15;
                double d = acc[fm][fn][j] + (double)bias[col];
                P64[(size_t)row * D_DIM + col] = d;
                float a = (float)d;
                part += a * a;
                Pbf[(size_t)row * D_DIM + col] = f2bf(a);
            }
            #pragma unroll
            for (int m = 1; m < 16; m <<= 1) part += __shfl_xor(part, m, 64);
            if (l15 == 0) atomicAdd(&qsq[row], part);
        }
    }
}

// ---- Kernel 1b: measure the actual within-16 row permutation of P64 ----
__global__ __launch_bounds__(256) void perm_detect_kernel(const float* __restrict__ Q,
                                                          const float* __restrict__ W,
                                                          const float* __restrict__ bias,
                                                          const double* __restrict__ P64,
                                                          int* __restrict__ invperm)
{
    __shared__ double tv[16];
    const int t = threadIdx.x;      // 256 threads
    const int g = t >> 4;           // true row 0..15
    const int s = t & 15;           // k-slice
    if (t < 16) invperm[t] = t;     // identity default (overwritten below)

    double acc = 0.0;
    const int kb = s * 64;
    for (int k = 0; k < 64; ++k)
        acc = fma((double)Q[(size_t)g * D_DIM + kb + k], (double)W[kb + k], acc);
    #pragma unroll
    for (int off = 8; off; off >>= 1) acc += __shfl_down(acc, off, 16);
    if (s == 0) tv[g] = acc + (double)bias[0];
    __syncthreads();

    if (t < 16) {
        double p = P64[(size_t)t * D_DIM];   // physical row t, col 0
        int best = 0; double bd = fabs(p - tv[0]);
        #pragma unroll
        for (int i = 1; i < 16; ++i) {
            double d = fabs(p - tv[i]);
            if (d < bd) { bd = d; best = i; }
        }
        invperm[best] = t;   // physical row t holds true row `best`
    }
}

// ---- Kernel 4: bf16-MFMA screening GEMM + per-lane register top-5 ----
// R14/R11 configuration (measured 231-233us, best of 7 structural variants).
__global__ __launch_bounds__(256, 2) void dist_mfma_kernel(const unsigned short* __restrict__ Pbf,
                                                           const unsigned short* __restrict__ Cbf,
                                                           const float* __restrict__ qsq,
                                                           const float* __restrict__ csq,
                                                           int* __restrict__ pi)
{
    __shared__ __align__(16) short CsS[CTILE * 64];  // 64 KB
    __shared__ __align__(16) short QsS[QT * 64];     //  8 KB
    float* MV = (float*)CsS;                         // merge alias: [64][4][TOPA]
    int*   MI = (int*)(CsS + 4096);                  // 8 KB offset

    const int t    = threadIdx.x;
    const int lane = t & 63;
    const int w    = t >> 6;       // wave 0..3 -> 128-context strip
    const int l15  = lane & 15;
    const int l4   = lane >> 4;    // 0..3
    const int r8   = lane >> 3;    // 0..7 (staging sub-row)
    const int sc   = lane & 7;     // staging store-chunk
    const int csplit = blockIdx.x;
    const int by = blockIdx.y;
    const int bz = blockIdx.z;
    const int qg0 = bz * NQ + by * QT;

    // loop-invariant lane-relative staging offsets (elements)
    unsigned cOff[16], qOff[2];
    #pragma unroll
    for (int j = 0; j < 16; ++j)
        cOff[j] = (unsigned)((w * 128 + j * 8 + r8) * D_DIM + (sc ^ r8) * 8);
    #pragma unroll
    for (int j = 0; j < 2; ++j)
        qOff[j] = (unsigned)((w * 16 + j * 8 + r8) * D_DIM + (sc ^ r8) * 8);

    float qsv[4];
    #pragma unroll
    for (int s = 0; s < 4; ++s) qsv[s] = qsq[qg0 + s * 16 + l15];

    float bv[4][TOPA]; int bi[4][TOPA];
    #pragma unroll
    for (int s = 0; s < 4; ++s)
        #pragma unroll
        for (int j = 0; j < TOPA; ++j) { bv[s][j] = FLT_MAX; bi[s][j] = 0x7fffffff; }

    const int cpb = NC / CSPLIT;   // 2048
    for (int it = 0; it < cpb / CTILE; ++it) {       // 4 iterations
        const int cg0 = csplit * cpb + it * CTILE;
        const size_t crow0 = (size_t)bz * NC + cg0;

        f32x4 acc[8][4];
        #pragma unroll
        for (int u = 0; u < 8; ++u)
            #pragma unroll
            for (int s = 0; s < 4; ++s) acc[u][s] = (f32x4)0.0f;

        for (int k0 = 0; k0 < D_DIM; k0 += BK) {
            const unsigned short* cB = Cbf + crow0 * D_DIM + k0;
            const unsigned short* qB = Pbf + (size_t)qg0 * D_DIM + k0;
            __syncthreads();   // all waves done reading previous LDS contents
            #pragma unroll
            for (int j = 0; j < 16; ++j)
                gload16(cB + cOff[j], &CsS[(w * 128 + j * 8) * 64]);
            #pragma unroll
            for (int j = 0; j < 2; ++j)
                gload16(qB + qOff[j], &QsS[(w * 16 + j * 8) * 64]);
            __syncthreads();   // vmcnt drained before barrier -> LDS filled
            #pragma unroll
            for (int ks = 0; ks < 2; ++ks) {
                const int sp = ((ks * 4 + l4) ^ (l15 & 7)) * 8;
                bf16x8 bq[4];
                #pragma unroll
                for (int s = 0; s < 4; ++s)
                    bq[s] = *(const bf16x8*)&QsS[(s * 16 + l15) * 64 + sp];
                #pragma unroll
                for (int u = 0; u < 8; ++u) {
                    bf16x8 ac = *(const bf16x8*)&CsS[(w * 128 + u * 16 + l15) * 64 + sp];
                    #pragma unroll
                    for (int s = 0; s < 4; ++s)
                        acc[u][s] = __builtin_amdgcn_mfma_f32_16x16x32_bf16(ac, bq[s], acc[u][s], 0, 0, 0);
                }
            }
        }

        // d^2 = |q|^2 + |c|^2 - 2 q.c  -> branchless per-lane register top-5
        #pragma unroll
        for (int u = 0; u < 8; ++u) {
            const int crow = w * 128 + u * 16 + l4 * 4;
            float4 cs4 = *(const float4*)&csq[(size_t)bz * NC + cg0 + crow];
            float csa[4] = {cs4.x, cs4.y, cs4.z, cs4.w};
            #pragma unroll
            for (int s = 0; s < 4; ++s) {
                #pragma unroll
                for (int r = 0; r < 4; ++r) {
                    float v = qsv[s] + csa[r] - 2.0f * acc[u][s][r];
                    ins5b(bv[s], bi[s], v, cg0 + crow + r);
                }
            }
        }
    }

    // wave-level merge across l4 groups (same query columns) via shuffles
    #pragma unroll
    for (int mask = 16; mask <= 32; mask <<= 1) {
        #pragma unroll
        for (int s = 0; s < 4; ++s) {
            float ov[TOPA]; int oi[TOPA];
            #pragma unroll
            for (int j = 0; j < TOPA; ++j) {
                ov[j] = __shfl_xor(bv[s][j], mask, 64);
                oi[j] = __shfl_xor(bi[s][j], mask, 64);
            }
            #pragma unroll
            for (int j = 0; j < TOPA; ++j) insN<TOPA>(bv[s], bi[s], ov[j], oi[j]);
        }
    }
    // cross-wave merge via LDS (l4==0 lanes hold wave-merged lists)
    __syncthreads();
    if (l4 == 0) {
        #pragma unroll
        for (int s = 0; s < 4; ++s) {
            int q = s * 16 + l15;
            #pragma unroll
            for (int j = 0; j < TOPA; ++j) {
                MV[(q * 4 + w) * TOPA + j] = bv[s][j];
                MI[(q * 4 + w) * TOPA + j] = bi[s][j];
            }
        }
    }
    __syncthreads();
    if (t < QT) {
        float mv[TOPA]; int mi[TOPA];
        #pragma unroll
        for (int j = 0; j < TOPA; ++j) { mv[j] = FLT_MAX; mi[j] = 0x7fffffff; }
        for (int l = 0; l < 4; ++l)
            #pragma unroll
            for (int j = 0; j < TOPA; ++j)
                insN<TOPA>(mv, mi, MV[(t * 4 + l) * TOPA + j], MI[(t * 4 + l) * TOPA + j]);
        size_t base = (((size_t)qg0 + t) * CSPLIT + csplit) * TOPA;
        #pragma unroll
        for (int j = 0; j < TOPA; ++j) pi[base + j] = mi[j];
    }
}

// ---- Kernel 5: fp64 exact refine of 40 candidates per query -> top-5, sqrt, outputs ----
__global__ __launch_bounds__(256) void refine_kernel(const double* __restrict__ P64,
                                                     const int* __restrict__ invperm,
                                                     const float* __restrict__ C,
                                                     const int*   __restrict__ pi,
                                                     float* __restrict__ out)
{
    __shared__ double pS[D_DIM];   // 8 KB staged P-row
    __shared__ double dvs[CAND];
    __shared__ int    dis[CAND];
    const int q    = blockIdx.x;                      // true row
    const int pq   = (q & ~15) | invperm[q & 15];     // physical row (P64, Pbf, pi)
    const int bz   = q >> 10;
    const int t    = threadIdx.x;
    const int wave = t >> 6;
    const int lane = t & 63;
    const double* p = P64 + (size_t)pq * D_DIM;

    #pragma unroll
    for (int j = 0; j < D_DIM / 256; ++j) pS[t + j * 256] = p[t + j * 256];
    __syncthreads();

    for (int k = wave; k < CAND; k += 4) {
        int ci = pi[(size_t)pq * CAND + k];
        const float* c = C + ((size_t)bz * NC + ci) * D_DIM;
        double s = 0.0;
        #pragma unroll
        for (int j = 0; j < 16; ++j) {
            int d = lane + 64 * j;
            double diff = pS[d] - (double)c[d];
            s = fma(diff, diff, s);
        }
        #pragma unroll
        for (int off = 32; off; off >>= 1) s += __shfl_down(s, off, 64);
        if (lane == 0) { dvs[k] = s; dis[k] = ci; }
    }
    __syncthreads();
    if (t == 0) {
        double bv[TOPN]; int bi[TOPN];
        #pragma unroll
        for (int j = 0; j < TOPN; ++j) { bv[j] = DBL_MAX; bi[j] = 0x7fffffff; }
        for (int k = 0; k < CAND; ++k)
            topk_insert<TOPN,double>(bv, bi, dvs[k], dis[k]);
        #pragma unroll
        for (int j = 0; j < TOPN; ++j) {
            out[(size_t)q * TOPN + j] = (float)sqrt(bv[j]);
            out[(size_t)B_DIM * NQ * TOPN + (size_t)q * TOPN + j] = (float)bi[j];
        }
    }
}

extern "C" void kernel_launch(void* const* d_in, const int* in_sizes, int n_in,
                              void* d_out, int out_size, void* d_ws, size_t ws_size,
                              hipStream_t stream) {
    const float* Q    = (const float*)d_in[0];
    const float* C    = (const float*)d_in[1];
    const float* W    = (const float*)d_in[2];
    const float* bias = (const float*)d_in[3];
    float* out = (float*)d_out;

    char* ws = (char*)d_ws;
    double*         P64 = (double*)ws;                                       // 32 MB
    unsigned short* Pbf = (unsigned short*)(ws + (size_t)32 * 1024 * 1024);  //  8 MB
    unsigned short* Cbf = (unsigned short*)(ws + (size_t)40 * 1024 * 1024);  // 128 MB
    float*          qsq = (float*)(ws + (size_t)168 * 1024 * 1024);          // 16 KB
    float*          csq = qsq + 4096;                                        // 256 KB
    int*            pi  = (int*)(csq + 65536);                               // 655 KB
    int*            ivp = pi + (size_t)B_DIM * NQ * CAND;                    // 64 B
    // total ~170 MB of workspace

    hipMemsetAsync(qsq, 0, (size_t)B_DIM * NQ * sizeof(float), stream);  // qsq accumulated by atomics
    proj_packc_kernel<<<PROJ_BLKS + (B_DIM * NC) / 4, 256, 0, stream>>>(Q, W, bias, C, P64, Pbf, qsq, Cbf, csq);
    perm_detect_kernel<<<1, 256, 0, stream>>>(Q, W, bias, P64, ivp);
    dist_mfma_kernel<<<dim3(CSPLIT, NQ / QT, B_DIM), 256, 0, stream>>>(Pbf, Cbf, qsq, csq, pi);
    refine_kernel<<<B_DIM * NQ, 256, 0, stream>>>(P64, ivp, C, pi, out);
}